// Round 1
// baseline (119.092 us; speedup 1.0000x reference)
//
#include <hip/hip_runtime.h>
#include <math.h>

#define COLORS 10
#define MAX_SHIFT 5
#define NB 32
#define H 128
#define W 128
#define NS 120          // 11*11 - 1 shifts
#define HW (H*W)

// s -> (dy,dx): dy outer -5..5, dx inner -5..5, (0,0) at linear 60 skipped
__device__ __forceinline__ void shift_of(int s, int& dy, int& dx) {
    int lin = s + (s >= 60 ? 1 : 0);
    dy = lin / 11 - 5;
    dx = lin % 11 - 5;
}

// match[b*NS+s] = sum over pixels of (shifted_demo_in == demo_out) * exp(clw[demo_out])
__global__ __launch_bounds__(256) void match_kernel(
    const int* __restrict__ demo_in, const int* __restrict__ demo_out,
    const float* __restrict__ clw, float* __restrict__ match)
{
    int blk = blockIdx.x;
    int b = blk / NS;
    int s = blk % NS;
    int dy, dx; shift_of(s, dy, dx);

    __shared__ float wexp[COLORS];
    int tid = threadIdx.x;
    if (tid < COLORS) wexp[tid] = expf(clw[tid]);
    __syncthreads();

    const int* __restrict__ din  = demo_in  + b * HW;
    const int* __restrict__ dout = demo_out + b * HW;

    float partial = 0.f;
    for (int i = tid; i < HW; i += 256) {
        int y = i >> 7, x = i & 127;
        int co = dout[i];
        int sy = y - dy, sx = x - dx;
        int v = 0;  // zero padding: OOB shifted value is color 0
        if (sy >= 0 && sy < H && sx >= 0 && sx < W) v = din[sy * W + sx];
        if (v == co) partial += wexp[co];
    }

    // 4-wave block reduction
    for (int off = 32; off > 0; off >>= 1)
        partial += __shfl_down(partial, off, 64);
    __shared__ float wsum[4];
    if ((tid & 63) == 0) wsum[tid >> 6] = partial;
    __syncthreads();
    if (tid == 0) match[blk] = wsum[0] + wsum[1] + wsum[2] + wsum[3];
}

// attention[b*NS+s] = softmax over s of match[b,s]/sqrt(HW)*min(exp(logit_scale),100)
__global__ __launch_bounds__(64) void softmax_kernel(
    const float* __restrict__ match, const float* __restrict__ logit_scale,
    float* __restrict__ attention)
{
    int b = blockIdx.x;
    int lane = threadIdx.x;
    float scale = fminf(expf(logit_scale[0]), 100.0f) / sqrtf((float)HW);

    int i0 = lane, i1 = lane + 64;
    float s0 = match[b * NS + i0] * scale;                      // i0 < 64 < NS always valid
    float s1 = (i1 < NS) ? match[b * NS + i1] * scale : -INFINITY;

    float m = fmaxf(s0, s1);
    for (int off = 32; off > 0; off >>= 1) m = fmaxf(m, __shfl_xor(m, off, 64));
    float e0 = expf(s0 - m);
    float e1 = (i1 < NS) ? expf(s1 - m) : 0.f;
    float sum = e0 + e1;
    for (int off = 32; off > 0; off >>= 1) sum += __shfl_xor(sum, off, 64);
    float inv = 1.0f / sum;
    attention[b * NS + i0] = e0 * inv;
    if (i1 < NS) attention[b * NS + i1] = e1 * inv;
}

// out[b,c,y,x] = log(max(sum_s attention[b,s] * (shifted_query[s,b,y,x]==c), 1e-6))
__global__ __launch_bounds__(128) void accum_kernel(
    const int* __restrict__ query_in, const float* __restrict__ attention,
    float* __restrict__ out)
{
    int blk = blockIdx.x;
    int b = blk >> 7;      // / H
    int y = blk & 127;     // % H
    int x = threadIdx.x;

    __shared__ float att[NS];
    if (threadIdx.x < NS) att[threadIdx.x] = attention[b * NS + threadIdx.x];
    __syncthreads();

    const int* __restrict__ q = query_in + b * HW;

    float acc[COLORS];
    #pragma unroll
    for (int c = 0; c < COLORS; c++) acc[c] = 0.f;

    #pragma unroll 4
    for (int s = 0; s < NS; s++) {
        int lin = s + (s >= 60 ? 1 : 0);
        int dy = lin / 11 - 5, dx = lin % 11 - 5;
        int sy = y - dy, sx = x - dx;
        int v = 0;  // zero padding: OOB shifted value is color 0
        if (sy >= 0 && sy < H && sx >= 0 && sx < W) v = q[sy * W + sx];
        float a = att[s];
        #pragma unroll
        for (int c = 0; c < COLORS; c++) acc[c] += (v == c) ? a : 0.f;
    }

    float* __restrict__ ob = out + (size_t)b * COLORS * HW + y * W + x;
    #pragma unroll
    for (int c = 0; c < COLORS; c++) ob[c * HW] = logf(fmaxf(acc[c], 1e-6f));
}

extern "C" void kernel_launch(void* const* d_in, const int* in_sizes, int n_in,
                              void* d_out, int out_size, void* d_ws, size_t ws_size,
                              hipStream_t stream) {
    const int*   demo_in     = (const int*)d_in[0];
    const int*   demo_out    = (const int*)d_in[1];
    const int*   query_in    = (const int*)d_in[2];
    const float* clw         = (const float*)d_in[3];
    const float* logit_scale = (const float*)d_in[4];
    float* out = (float*)d_out;

    float* match     = (float*)d_ws;        // NB*NS floats
    float* attention = match + NB * NS;     // NB*NS floats

    match_kernel<<<NB * NS, 256, 0, stream>>>(demo_in, demo_out, clw, match);
    softmax_kernel<<<NB, 64, 0, stream>>>(match, logit_scale, attention);
    accum_kernel<<<NB * H, 128, 0, stream>>>(query_in, attention, out);
}